// Round 5
// baseline (466.959 us; speedup 1.0000x reference)
//
#include <hip/hip_runtime.h>

// Butterfly multiply, B=16384, N=2048, LOG_N=11, increasing stride.
// Element layout: e = r*128 + lane*2 + j   (r in [0,16), j in {0,1})
// Register k = 2*r + j. Stage st (s=2^st), p = ((e>>(st+1))<<st) | (e & (s-1)),
// twiddle flat: st*4096 + 4*p + 2*i + jj.
//   stage 0      (s=1)        : pair = j bit, in-lane, global float4 twiddle
//   stages 1..6  (s=2..64)    : pair = lane bit (st-1) -> DPP / ds_swizzle / shfl
//   stages 7..10 (s=128..1024): pair = r bit (st-7), in-register
//
// R9 == R8 resubmitted (R8 died to a container-acquire infra failure, never
// reached the chip). Spill root-cause from R5/R6/R7: __launch_bounds__ sets
// only MIN waves/EU; the backend occupancy heuristic clamps VGPRs to the
// next occupancy step above it (84@min3, 64@min4, 128@min2) and SPILLS the
// 64-reg v[][] to meet that self-imposed target. True peak pressure here is
// ~160 regs (64 v + hoisted in-flight ds_read twiddles + addressing). Fix:
// pin min=max=2 waves/EU -> 256-reg budget, no occupancy-chasing spill.
// Also pin flat_work_group_size(256,256) explicitly (defensive).
// CRITICAL (R4 lesson): every loop fully unrolled; all v[][] indices
// compile-time, else scratch allocation.

constexpr int BATCH = 16384;
constexpr int N = 2048;
constexpr int ROWS = 2;             // rows per wave
constexpr int WPB = 4;              // waves per block
constexpr int BLOCK = 64 * WPB;     // 256 threads
constexpr int GRID = BATCH / (ROWS * WPB);   // 2048 blocks

// Read-side LDS word-address swizzle: XOR bit5->bit2, bit6->bit3.
// Involution; preserves float2 (8B) and float4 (16B) alignment.
__device__ __forceinline__ int swz(int a) {
    return a ^ (((a >> 5) & 1) << 2) ^ (((a >> 6) & 1) << 3);
}

// Cross-lane partner (lane ^ M), cheapest pipe per mask.
template <int M>
__device__ __forceinline__ float part_xor(float x) {
    if constexpr (M == 1)        // quad_perm [1,0,3,2]
        return __int_as_float(__builtin_amdgcn_mov_dpp(__float_as_int(x), 0xB1, 0xF, 0xF, true));
    else if constexpr (M == 2)   // quad_perm [2,3,0,1]
        return __int_as_float(__builtin_amdgcn_mov_dpp(__float_as_int(x), 0x4E, 0xF, 0xF, true));
    else if constexpr (M == 4)   // xor 4 within 32-half
        return __int_as_float(__builtin_amdgcn_ds_swizzle(__float_as_int(x), 0x101F));
    else if constexpr (M == 8)
        return __int_as_float(__builtin_amdgcn_ds_swizzle(__float_as_int(x), 0x201F));
    else if constexpr (M == 16)
        return __int_as_float(__builtin_amdgcn_ds_swizzle(__float_as_int(x), 0x401F));
    else
        return __shfl_xor(x, 32, 64);
}

// stages 1..6 (s=2..64): pair bit is a lane bit -> cross-lane partner
template <int ST>
__device__ __forceinline__ void mid_stage(float (&v)[ROWS][32], const float* twb, int lane) {
    constexpr int s = 1 << ST;
    constexpr int m = 1 << (ST - 1);
    const int hiHalf = (lane >> (ST - 1)) & 1;
    const int l2 = lane * 2;
    #pragma unroll
    for (int k = 0; k < 32; ++k) {
        const int e = (k >> 1) * 128 + l2 + (k & 1);
        const int p = ((e >> (ST + 1)) << ST) | (e & (s - 1));
        const int a = swz(4 * p + 2 * hiHalf);
        const float2 t2 = *(const float2*)(twb + a);
        #pragma unroll
        for (int rr = 0; rr < ROWS; ++rr) {
            const float mine = v[rr][k];
            const float part = part_xor<m>(mine);
            const float lo = hiHalf ? part : mine;
            const float hi = hiHalf ? mine : part;
            v[rr][k] = fmaf(t2.x, lo, t2.y * hi);
        }
    }
}

// stages 7..10 (s=128..1024): pair bit is an r bit -> in-register
template <int ST>
__device__ __forceinline__ void hi_stage(float (&v)[ROWS][32], const float* twb, int lane) {
    constexpr int s = 1 << ST;
    constexpr int rm = 1 << (ST - 7);
    const int l2 = lane * 2;
    #pragma unroll
    for (int r = 0; r < 16; ++r) {
        if (r & rm) continue;                  // visit each pair at lo (compile-time)
        #pragma unroll
        for (int j = 0; j < 2; ++j) {
            const int e = r * 128 + l2 + j;
            const int p = ((e >> (ST + 1)) << ST) | (e & (s - 1));
            const int a = swz(4 * p);
            const float4 t4 = *(const float4*)(twb + a);
            const int klo = 2 * r + j;
            const int khi = 2 * (r + rm) + j;
            #pragma unroll
            for (int rr = 0; rr < ROWS; ++rr) {
                const float lo = v[rr][klo];
                const float hi = v[rr][khi];
                v[rr][klo] = fmaf(t4.x, lo, t4.y * hi);
                v[rr][khi] = fmaf(t4.z, lo, t4.w * hi);
            }
        }
    }
}

__global__
__attribute__((amdgpu_flat_work_group_size(256, 256)))
__attribute__((amdgpu_waves_per_eu(2, 2)))
void butterfly_kernel(const float* __restrict__ x,
                      const float* __restrict__ tw,
                      const float* __restrict__ bias,
                      float* __restrict__ out)
{
    __shared__ __align__(16) float lds[2][4096];   // 2 x 16 KiB stage tables
    const int tid = threadIdx.x;
    const int lane = tid & 63;
    const int w = tid >> 6;
    const int wid = blockIdx.x * WPB + w;
    const size_t row0 = (size_t)wid * ROWS;
    const int l2 = lane * 2;

    // DMA stage st's 16 KiB table into lds[buf]. LDS dest is wave-uniform
    // (HW adds lane*16); global src is per-lane and carries the swizzle.
    auto stage_tw = [&](int st, int buf) {
        const float* base = tw + (st << 12);
        #pragma unroll
        for (int i = 0; i < 4; ++i) {
            const int s = i * 256 + (w << 6) + lane;            // linear float4 slot
            const int g = s ^ ((s >> 3) & 1) ^ (((s >> 4) & 1) << 1); // swizzled src
            __builtin_amdgcn_global_load_lds(
                (const __attribute__((address_space(1))) void*)(base + 4 * g),
                (__attribute__((address_space(3))) void*)(&lds[buf][(i * 256 + (w << 6)) * 4]),
                16, 0, 0);
        }
    };

    stage_tw(1, 1);     // prefetch stage-1 table under x-load + stage 0

    float v[ROWS][32];

    // ---- coalesced float2 x loads (512 B per wave-inst)
    #pragma unroll
    for (int rr = 0; rr < ROWS; ++rr) {
        const float* src = x + (row0 + rr) * N + l2;
        #pragma unroll
        for (int r = 0; r < 16; ++r) {
            const float2 f = *(const float2*)(src + r * 128);
            v[rr][2*r]   = f.x;
            v[rr][2*r+1] = f.y;
        }
    }

    // ---- stage 0 (s=1): in-lane pair, twiddle straight from global
    // (perfectly coalesced float4, L2-resident; stays off the LDS pipeline)
    #pragma unroll
    for (int r = 0; r < 16; ++r) {
        const float4 t4 = *(const float4*)(tw + 4 * (r * 64 + lane));
        #pragma unroll
        for (int rr = 0; rr < ROWS; ++rr) {
            const float lo = v[rr][2*r];
            const float hi = v[rr][2*r+1];
            v[rr][2*r]   = fmaf(t4.x, lo, t4.y * hi);
            v[rr][2*r+1] = fmaf(t4.z, lo, t4.w * hi);
        }
    }
    __syncthreads();    // vmcnt drain: stage-1 table landed for all waves

    // Steady state: prefetch st+1 into the idle buffer (its readers finished
    // at the previous barrier), compute st from the fresh buffer, barrier
    // (drains the prefetch + all ds_reads).
    stage_tw(2, 0);  mid_stage<1>(v, &lds[1][0], lane); __syncthreads();
    stage_tw(3, 1);  mid_stage<2>(v, &lds[0][0], lane); __syncthreads();
    stage_tw(4, 0);  mid_stage<3>(v, &lds[1][0], lane); __syncthreads();
    stage_tw(5, 1);  mid_stage<4>(v, &lds[0][0], lane); __syncthreads();
    stage_tw(6, 0);  mid_stage<5>(v, &lds[1][0], lane); __syncthreads();
    stage_tw(7, 1);  mid_stage<6>(v, &lds[0][0], lane); __syncthreads();
    stage_tw(8, 0);  hi_stage<7>(v, &lds[1][0], lane);  __syncthreads();
    stage_tw(9, 1);  hi_stage<8>(v, &lds[0][0], lane);  __syncthreads();
    stage_tw(10, 0); hi_stage<9>(v, &lds[1][0], lane);  __syncthreads();
    hi_stage<10>(v, &lds[0][0], lane);

    // ---- coalesced float2 stores with bias
    #pragma unroll
    for (int r = 0; r < 16; ++r) {
        const float2 b = *(const float2*)(bias + r * 128 + l2);
        #pragma unroll
        for (int rr = 0; rr < ROWS; ++rr) {
            float2 o;
            o.x = v[rr][2*r]   + b.x;
            o.y = v[rr][2*r+1] + b.y;
            *(float2*)(out + (row0 + rr) * N + r * 128 + l2) = o;
        }
    }
}

extern "C" void kernel_launch(void* const* d_in, const int* in_sizes, int n_in,
                              void* d_out, int out_size, void* d_ws, size_t ws_size,
                              hipStream_t stream) {
    const float* x    = (const float*)d_in[0];
    const float* tw   = (const float*)d_in[1];
    const float* bias = (const float*)d_in[2];
    float* out = (float*)d_out;

    butterfly_kernel<<<GRID, BLOCK, 0, stream>>>(x, tw, bias, out);
}

// Round 6
// 431.107 us; speedup vs baseline: 1.0832x; 1.0832x over previous
//
#include <hip/hip_runtime.h>

// Butterfly multiply, B=16384, N=2048, LOG_N=11, increasing stride.
// Element layout: e = r*128 + lane*2 + j   (r in [0,16), j in {0,1})
// Register k = 2*r + j. Stage st (s=2^st), p = ((e>>(st+1))<<st) | (e & (s-1)),
// twiddle flat: st*4096 + 4*p + 2*i + jj.
//   stage 0      (s=1)        : pair = j bit, in-lane, global float4 twiddle
//   stages 1..6  (s=2..64)    : pair = lane bit (st-1) -> DPP / ds_swizzle / shfl
//   stages 7..10 (s=128..1024): pair = r bit (st-7), in-register
//
// R10: pressure-capping fences. R7/R9 proved the spill is NOT a budget clamp
// (launch_bounds(256,2) already allows 256 regs; waves_per_eu(2,2) changed
// nothing): the pre-RA scheduler hoists all 32 ds_read twiddle loads per
// stage (64 regs) on top of the 64-reg v[][], RA spills v to scratch
// (R9: +510MB write = ~3.8 spill-stores of v, +256MB fetch = ~1.9 reloads).
// Fix: asm volatile memory-clobber fences every 4 twiddle loads inside the
// unrolled stage loops. Orders MEMORY ops only (caps in-flight ds_reads at
// ~4 = 8-16 regs); ds_swizzle/DPP/shfl are no-mem intrinsics and the fma
// chains are registers-only -> unaffected. All fence predicates are
// compile-time ((k&3)==3) inside fully-unrolled loops (R4 lesson: no
// dynamic v[][] indexing). Expected pressure: 64 v + ~16 tw + ~20 temps
// ~= 100 regs -> no spill, 5 blocks/CU (LDS 160KiB exactly).
// CRITICAL (R4 lesson): every loop fully unrolled; all v[][] indices
// compile-time, else scratch allocation.

constexpr int BATCH = 16384;
constexpr int N = 2048;
constexpr int ROWS = 2;             // rows per wave
constexpr int WPB = 4;              // waves per block
constexpr int BLOCK = 64 * WPB;     // 256 threads
constexpr int GRID = BATCH / (ROWS * WPB);   // 2048 blocks

// Scheduler fence: memory ops cannot be reordered across this. Caps the
// number of in-flight ds_read twiddle loads (register pressure), costs no
// instructions.
#define SCHED_FENCE() asm volatile("" ::: "memory")

// Read-side LDS word-address swizzle: XOR bit5->bit2, bit6->bit3.
// Involution; preserves float2 (8B) and float4 (16B) alignment.
__device__ __forceinline__ int swz(int a) {
    return a ^ (((a >> 5) & 1) << 2) ^ (((a >> 6) & 1) << 3);
}

// Cross-lane partner (lane ^ M), cheapest pipe per mask.
template <int M>
__device__ __forceinline__ float part_xor(float x) {
    if constexpr (M == 1)        // quad_perm [1,0,3,2]
        return __int_as_float(__builtin_amdgcn_mov_dpp(__float_as_int(x), 0xB1, 0xF, 0xF, true));
    else if constexpr (M == 2)   // quad_perm [2,3,0,1]
        return __int_as_float(__builtin_amdgcn_mov_dpp(__float_as_int(x), 0x4E, 0xF, 0xF, true));
    else if constexpr (M == 4)   // xor 4 within 32-half
        return __int_as_float(__builtin_amdgcn_ds_swizzle(__float_as_int(x), 0x101F));
    else if constexpr (M == 8)
        return __int_as_float(__builtin_amdgcn_ds_swizzle(__float_as_int(x), 0x201F));
    else if constexpr (M == 16)
        return __int_as_float(__builtin_amdgcn_ds_swizzle(__float_as_int(x), 0x401F));
    else
        return __shfl_xor(x, 32, 64);
}

// stages 1..6 (s=2..64): pair bit is a lane bit -> cross-lane partner
template <int ST>
__device__ __forceinline__ void mid_stage(float (&v)[ROWS][32], const float* twb, int lane) {
    constexpr int s = 1 << ST;
    constexpr int m = 1 << (ST - 1);
    const int hiHalf = (lane >> (ST - 1)) & 1;
    const int l2 = lane * 2;
    #pragma unroll
    for (int k = 0; k < 32; ++k) {
        const int e = (k >> 1) * 128 + l2 + (k & 1);
        const int p = ((e >> (ST + 1)) << ST) | (e & (s - 1));
        const int a = swz(4 * p + 2 * hiHalf);
        const float2 t2 = *(const float2*)(twb + a);
        #pragma unroll
        for (int rr = 0; rr < ROWS; ++rr) {
            const float mine = v[rr][k];
            const float part = part_xor<m>(mine);
            const float lo = hiHalf ? part : mine;
            const float hi = hiHalf ? mine : part;
            v[rr][k] = fmaf(t2.x, lo, t2.y * hi);
        }
        if ((k & 3) == 3) SCHED_FENCE();   // cap in-flight ds_reads at 4
    }
}

// stages 7..10 (s=128..1024): pair bit is an r bit -> in-register
template <int ST>
__device__ __forceinline__ void hi_stage(float (&v)[ROWS][32], const float* twb, int lane) {
    constexpr int s = 1 << ST;
    constexpr int rm = 1 << (ST - 7);
    const int l2 = lane * 2;
    #pragma unroll
    for (int r = 0; r < 16; ++r) {
        if (r & rm) continue;                  // visit each pair at lo (compile-time)
        #pragma unroll
        for (int j = 0; j < 2; ++j) {
            const int e = r * 128 + l2 + j;
            const int p = ((e >> (ST + 1)) << ST) | (e & (s - 1));
            const int a = swz(4 * p);
            const float4 t4 = *(const float4*)(twb + a);
            const int klo = 2 * r + j;
            const int khi = 2 * (r + rm) + j;
            #pragma unroll
            for (int rr = 0; rr < ROWS; ++rr) {
                const float lo = v[rr][klo];
                const float hi = v[rr][khi];
                v[rr][klo] = fmaf(t4.x, lo, t4.y * hi);
                v[rr][khi] = fmaf(t4.z, lo, t4.w * hi);
            }
        }
        if ((r & 1) == 1) SCHED_FENCE();   // cap in-flight b128 reads at ~4
    }
}

__global__ __launch_bounds__(BLOCK, 2)
void butterfly_kernel(const float* __restrict__ x,
                      const float* __restrict__ tw,
                      const float* __restrict__ bias,
                      float* __restrict__ out)
{
    __shared__ __align__(16) float lds[2][4096];   // 2 x 16 KiB stage tables
    const int tid = threadIdx.x;
    const int lane = tid & 63;
    const int w = tid >> 6;
    const int wid = blockIdx.x * WPB + w;
    const size_t row0 = (size_t)wid * ROWS;
    const int l2 = lane * 2;

    // DMA stage st's 16 KiB table into lds[buf]. LDS dest is wave-uniform
    // (HW adds lane*16); global src is per-lane and carries the swizzle.
    auto stage_tw = [&](int st, int buf) {
        const float* base = tw + (st << 12);
        #pragma unroll
        for (int i = 0; i < 4; ++i) {
            const int s = i * 256 + (w << 6) + lane;            // linear float4 slot
            const int g = s ^ ((s >> 3) & 1) ^ (((s >> 4) & 1) << 1); // swizzled src
            __builtin_amdgcn_global_load_lds(
                (const __attribute__((address_space(1))) void*)(base + 4 * g),
                (__attribute__((address_space(3))) void*)(&lds[buf][(i * 256 + (w << 6)) * 4]),
                16, 0, 0);
        }
    };

    stage_tw(1, 1);     // prefetch stage-1 table under x-load + stage 0

    float v[ROWS][32];

    // ---- coalesced float2 x loads (512 B per wave-inst). These write
    // v[][] directly (in-flight pressure IS v), no fence needed.
    #pragma unroll
    for (int rr = 0; rr < ROWS; ++rr) {
        const float* src = x + (row0 + rr) * N + l2;
        #pragma unroll
        for (int r = 0; r < 16; ++r) {
            const float2 f = *(const float2*)(src + r * 128);
            v[rr][2*r]   = f.x;
            v[rr][2*r+1] = f.y;
        }
    }

    // ---- stage 0 (s=1): in-lane pair, twiddle straight from global
    // (perfectly coalesced float4, L2-resident; stays off the LDS pipeline).
    // Fence every 4 float4 loads: caps in-flight at 16 regs.
    #pragma unroll
    for (int r = 0; r < 16; ++r) {
        const float4 t4 = *(const float4*)(tw + 4 * (r * 64 + lane));
        #pragma unroll
        for (int rr = 0; rr < ROWS; ++rr) {
            const float lo = v[rr][2*r];
            const float hi = v[rr][2*r+1];
            v[rr][2*r]   = fmaf(t4.x, lo, t4.y * hi);
            v[rr][2*r+1] = fmaf(t4.z, lo, t4.w * hi);
        }
        if ((r & 3) == 3) SCHED_FENCE();
    }
    __syncthreads();    // vmcnt drain: stage-1 table landed for all waves

    // Steady state: prefetch st+1 into the idle buffer (its readers finished
    // at the previous barrier), compute st from the fresh buffer, barrier
    // (drains the prefetch + all ds_reads).
    stage_tw(2, 0);  mid_stage<1>(v, &lds[1][0], lane); __syncthreads();
    stage_tw(3, 1);  mid_stage<2>(v, &lds[0][0], lane); __syncthreads();
    stage_tw(4, 0);  mid_stage<3>(v, &lds[1][0], lane); __syncthreads();
    stage_tw(5, 1);  mid_stage<4>(v, &lds[0][0], lane); __syncthreads();
    stage_tw(6, 0);  mid_stage<5>(v, &lds[1][0], lane); __syncthreads();
    stage_tw(7, 1);  mid_stage<6>(v, &lds[0][0], lane); __syncthreads();
    stage_tw(8, 0);  hi_stage<7>(v, &lds[1][0], lane);  __syncthreads();
    stage_tw(9, 1);  hi_stage<8>(v, &lds[0][0], lane);  __syncthreads();
    stage_tw(10, 0); hi_stage<9>(v, &lds[1][0], lane);  __syncthreads();
    hi_stage<10>(v, &lds[0][0], lane);

    // ---- coalesced float2 stores with bias
    #pragma unroll
    for (int r = 0; r < 16; ++r) {
        const float2 b = *(const float2*)(bias + r * 128 + l2);
        #pragma unroll
        for (int rr = 0; rr < ROWS; ++rr) {
            float2 o;
            o.x = v[rr][2*r]   + b.x;
            o.y = v[rr][2*r+1] + b.y;
            *(float2*)(out + (row0 + rr) * N + r * 128 + l2) = o;
        }
    }
}

extern "C" void kernel_launch(void* const* d_in, const int* in_sizes, int n_in,
                              void* d_out, int out_size, void* d_ws, size_t ws_size,
                              hipStream_t stream) {
    const float* x    = (const float*)d_in[0];
    const float* tw   = (const float*)d_in[1];
    const float* bias = (const float*)d_in[2];
    float* out = (float*)d_out;

    butterfly_kernel<<<GRID, BLOCK, 0, stream>>>(x, tw, bias, out);
}

// Round 7
// 336.780 us; speedup vs baseline: 1.3865x; 1.2801x over previous
//
#include <hip/hip_runtime.h>

// Butterfly multiply, B=16384, N=2048, LOG_N=11, increasing stride.
// Element layout: e = r*128 + lane*2 + j   (r in [0,16), j in {0,1})
// Register k = 2*r + j. Stage st (s=2^st), p = ((e>>(st+1))<<st) | (e & (s-1)),
// twiddle flat: st*4096 + 4*p + 2*i + jj.
//   stage 0      (s=1)        : pair = j bit, in-lane, global float4 twiddle
//   stages 1..6  (s=2..64)    : pair = lane bit (st-1) -> DPP / ds_swizzle / shfl
//   stages 7..10 (s=128..1024): pair = r bit (st-7), in-register
//
// R11: the spill series reveals an empirical RA law on this toolchain:
// granted VGPRs = 512/(2 x declared_min_waves_per_EU):
//   min=2 -> 128 (R7/R9/R10), min=3 -> 84 (R5), min=4 -> 64 (R6).
// The backend sizes the budget for DOUBLE the declared minimum and spills
// to meet it; waves_per_eu(2,2) was a no-op (same min). This structure's
// true pressure is ~160 regs (64 v[][] + in-flight LDS twiddle reads +
// temps), so every min>=2 config spilled. Fix: declare min=1 -> budget
// 512/2 = 256 regs. Everything else identical to R10 (fences retained) --
// finally a clean test of the LDS twiddle pipeline.
// CRITICAL (R4 lesson): every loop fully unrolled; all v[][] indices
// compile-time, else scratch allocation.

constexpr int BATCH = 16384;
constexpr int N = 2048;
constexpr int ROWS = 2;             // rows per wave
constexpr int WPB = 4;              // waves per block
constexpr int BLOCK = 64 * WPB;     // 256 threads
constexpr int GRID = BATCH / (ROWS * WPB);   // 2048 blocks

// Scheduler fence: memory ops cannot be reordered across this. Caps the
// number of in-flight ds_read twiddle loads (register pressure), costs no
// instructions.
#define SCHED_FENCE() asm volatile("" ::: "memory")

// Read-side LDS word-address swizzle: XOR bit5->bit2, bit6->bit3.
// Involution; preserves float2 (8B) and float4 (16B) alignment.
__device__ __forceinline__ int swz(int a) {
    return a ^ (((a >> 5) & 1) << 2) ^ (((a >> 6) & 1) << 3);
}

// Cross-lane partner (lane ^ M), cheapest pipe per mask.
template <int M>
__device__ __forceinline__ float part_xor(float x) {
    if constexpr (M == 1)        // quad_perm [1,0,3,2]
        return __int_as_float(__builtin_amdgcn_mov_dpp(__float_as_int(x), 0xB1, 0xF, 0xF, true));
    else if constexpr (M == 2)   // quad_perm [2,3,0,1]
        return __int_as_float(__builtin_amdgcn_mov_dpp(__float_as_int(x), 0x4E, 0xF, 0xF, true));
    else if constexpr (M == 4)   // xor 4 within 32-half
        return __int_as_float(__builtin_amdgcn_ds_swizzle(__float_as_int(x), 0x101F));
    else if constexpr (M == 8)
        return __int_as_float(__builtin_amdgcn_ds_swizzle(__float_as_int(x), 0x201F));
    else if constexpr (M == 16)
        return __int_as_float(__builtin_amdgcn_ds_swizzle(__float_as_int(x), 0x401F));
    else
        return __shfl_xor(x, 32, 64);
}

// stages 1..6 (s=2..64): pair bit is a lane bit -> cross-lane partner
template <int ST>
__device__ __forceinline__ void mid_stage(float (&v)[ROWS][32], const float* twb, int lane) {
    constexpr int s = 1 << ST;
    constexpr int m = 1 << (ST - 1);
    const int hiHalf = (lane >> (ST - 1)) & 1;
    const int l2 = lane * 2;
    #pragma unroll
    for (int k = 0; k < 32; ++k) {
        const int e = (k >> 1) * 128 + l2 + (k & 1);
        const int p = ((e >> (ST + 1)) << ST) | (e & (s - 1));
        const int a = swz(4 * p + 2 * hiHalf);
        const float2 t2 = *(const float2*)(twb + a);
        #pragma unroll
        for (int rr = 0; rr < ROWS; ++rr) {
            const float mine = v[rr][k];
            const float part = part_xor<m>(mine);
            const float lo = hiHalf ? part : mine;
            const float hi = hiHalf ? mine : part;
            v[rr][k] = fmaf(t2.x, lo, t2.y * hi);
        }
        if ((k & 3) == 3) SCHED_FENCE();   // cap in-flight ds_reads at 4
    }
}

// stages 7..10 (s=128..1024): pair bit is an r bit -> in-register
template <int ST>
__device__ __forceinline__ void hi_stage(float (&v)[ROWS][32], const float* twb, int lane) {
    constexpr int s = 1 << ST;
    constexpr int rm = 1 << (ST - 7);
    const int l2 = lane * 2;
    #pragma unroll
    for (int r = 0; r < 16; ++r) {
        if (r & rm) continue;                  // visit each pair at lo (compile-time)
        #pragma unroll
        for (int j = 0; j < 2; ++j) {
            const int e = r * 128 + l2 + j;
            const int p = ((e >> (ST + 1)) << ST) | (e & (s - 1));
            const int a = swz(4 * p);
            const float4 t4 = *(const float4*)(twb + a);
            const int klo = 2 * r + j;
            const int khi = 2 * (r + rm) + j;
            #pragma unroll
            for (int rr = 0; rr < ROWS; ++rr) {
                const float lo = v[rr][klo];
                const float hi = v[rr][khi];
                v[rr][klo] = fmaf(t4.x, lo, t4.y * hi);
                v[rr][khi] = fmaf(t4.z, lo, t4.w * hi);
            }
        }
        if ((r & 1) == 1) SCHED_FENCE();   // cap in-flight b128 reads at ~4
    }
}

__global__ __launch_bounds__(BLOCK, 1)
void butterfly_kernel(const float* __restrict__ x,
                      const float* __restrict__ tw,
                      const float* __restrict__ bias,
                      float* __restrict__ out)
{
    __shared__ __align__(16) float lds[2][4096];   // 2 x 16 KiB stage tables
    const int tid = threadIdx.x;
    const int lane = tid & 63;
    const int w = tid >> 6;
    const int wid = blockIdx.x * WPB + w;
    const size_t row0 = (size_t)wid * ROWS;
    const int l2 = lane * 2;

    // DMA stage st's 16 KiB table into lds[buf]. LDS dest is wave-uniform
    // (HW adds lane*16); global src is per-lane and carries the swizzle.
    auto stage_tw = [&](int st, int buf) {
        const float* base = tw + (st << 12);
        #pragma unroll
        for (int i = 0; i < 4; ++i) {
            const int s = i * 256 + (w << 6) + lane;            // linear float4 slot
            const int g = s ^ ((s >> 3) & 1) ^ (((s >> 4) & 1) << 1); // swizzled src
            __builtin_amdgcn_global_load_lds(
                (const __attribute__((address_space(1))) void*)(base + 4 * g),
                (__attribute__((address_space(3))) void*)(&lds[buf][(i * 256 + (w << 6)) * 4]),
                16, 0, 0);
        }
    };

    stage_tw(1, 1);     // prefetch stage-1 table under x-load + stage 0

    float v[ROWS][32];

    // ---- coalesced float2 x loads (512 B per wave-inst). These write
    // v[][] directly (in-flight pressure IS v), no fence needed.
    #pragma unroll
    for (int rr = 0; rr < ROWS; ++rr) {
        const float* src = x + (row0 + rr) * N + l2;
        #pragma unroll
        for (int r = 0; r < 16; ++r) {
            const float2 f = *(const float2*)(src + r * 128);
            v[rr][2*r]   = f.x;
            v[rr][2*r+1] = f.y;
        }
    }

    // ---- stage 0 (s=1): in-lane pair, twiddle straight from global
    // (perfectly coalesced float4, L2-resident; stays off the LDS pipeline).
    // Fence every 4 float4 loads: caps in-flight at 16 regs.
    #pragma unroll
    for (int r = 0; r < 16; ++r) {
        const float4 t4 = *(const float4*)(tw + 4 * (r * 64 + lane));
        #pragma unroll
        for (int rr = 0; rr < ROWS; ++rr) {
            const float lo = v[rr][2*r];
            const float hi = v[rr][2*r+1];
            v[rr][2*r]   = fmaf(t4.x, lo, t4.y * hi);
            v[rr][2*r+1] = fmaf(t4.z, lo, t4.w * hi);
        }
        if ((r & 3) == 3) SCHED_FENCE();
    }
    __syncthreads();    // vmcnt drain: stage-1 table landed for all waves

    // Steady state: prefetch st+1 into the idle buffer (its readers finished
    // at the previous barrier), compute st from the fresh buffer, barrier
    // (drains the prefetch + all ds_reads).
    stage_tw(2, 0);  mid_stage<1>(v, &lds[1][0], lane); __syncthreads();
    stage_tw(3, 1);  mid_stage<2>(v, &lds[0][0], lane); __syncthreads();
    stage_tw(4, 0);  mid_stage<3>(v, &lds[1][0], lane); __syncthreads();
    stage_tw(5, 1);  mid_stage<4>(v, &lds[0][0], lane); __syncthreads();
    stage_tw(6, 0);  mid_stage<5>(v, &lds[1][0], lane); __syncthreads();
    stage_tw(7, 1);  mid_stage<6>(v, &lds[0][0], lane); __syncthreads();
    stage_tw(8, 0);  hi_stage<7>(v, &lds[1][0], lane);  __syncthreads();
    stage_tw(9, 1);  hi_stage<8>(v, &lds[0][0], lane);  __syncthreads();
    stage_tw(10, 0); hi_stage<9>(v, &lds[1][0], lane);  __syncthreads();
    hi_stage<10>(v, &lds[0][0], lane);

    // ---- coalesced float2 stores with bias
    #pragma unroll
    for (int r = 0; r < 16; ++r) {
        const float2 b = *(const float2*)(bias + r * 128 + l2);
        #pragma unroll
        for (int rr = 0; rr < ROWS; ++rr) {
            float2 o;
            o.x = v[rr][2*r]   + b.x;
            o.y = v[rr][2*r+1] + b.y;
            *(float2*)(out + (row0 + rr) * N + r * 128 + l2) = o;
        }
    }
}

extern "C" void kernel_launch(void* const* d_in, const int* in_sizes, int n_in,
                              void* d_out, int out_size, void* d_ws, size_t ws_size,
                              hipStream_t stream) {
    const float* x    = (const float*)d_in[0];
    const float* tw   = (const float*)d_in[1];
    const float* bias = (const float*)d_in[2];
    float* out = (float*)d_out;

    butterfly_kernel<<<GRID, BLOCK, 0, stream>>>(x, tw, bias, out);
}

// Round 8
// 323.407 us; speedup vs baseline: 1.4439x; 1.0414x over previous
//
#include <hip/hip_runtime.h>

// Butterfly multiply, B=16384, N=2048, LOG_N=11, increasing stride.
// Element layout: e = r*128 + lane*2 + j   (r in [0,16), j in {0,1})
// Register k = 2*r + j. Stage st (s=2^st), p = ((e>>(st+1))<<st) | (e & (s-1)),
// twiddle flat: st*4096 + 4*p + 2*i + jj.
//   stage 0      (s=1)        : pair = j bit, in-lane, global float4 twiddle
//   stages 1..6  (s=2..64)    : pair = lane bit (st-1) -> DPP / ds_swizzle / shfl
//   stages 7..10 (s=128..1024): pair = r bit (st-7), in-register
//
// R12: LDS twiddle pipeline VERDICT (R11, first clean run): 190us > R0's
// 145us. It moved 272 twiddle loads onto the LDS pipe that already carries
// ~256 shuffle ops/wave (~4-5K cyc/wave serialized) + 11 block barriers at
// 2 resident blocks/CU. L2 latency is hideable; LDS-pipe throughput and
// barriers are not. DROPPED: no LDS, no barriers, twiddles L2-direct.
// KEPT from the arc: launch_bounds(BLOCK,1) -> ~256-reg budget, no spill
// (R11: VGPR=224, WRITE=131072 exactly). Spent on ROWS=4:
//   - 272 twiddle loads/wave serve 4 rows (per-row traffic halves;
//     total twiddle loads 2.23M -> 1.11M).
//   - big budget lets the scheduler hoist next-stage (data-independent)
//     twiddle loads under current-stage FMAs = the ILP R0's 88 regs
//     couldn't afford. Light fences bound the hoist (~32 regs in flight):
//     pressure ~= 128 v + 32 loads + ~30 temps < 224.
//   - mid-stage select refactor: coefficients cm/cp via 2 cndmask per k
//     SHARED across rows (was 2 per row): out = cm*mine + cp*part.
//     Verified algebraically vs R0 for hiHalf=0/1.
// CRITICAL (R4 lesson): every loop fully unrolled; all v[][] indices
// compile-time, else scratch allocation.

constexpr int BATCH = 16384;
constexpr int N = 2048;
constexpr int ROWS = 4;             // rows per wave (twiddle amortization)
constexpr int WPB = 4;              // waves per block
constexpr int BLOCK = 64 * WPB;     // 256 threads
constexpr int GRID = BATCH / (ROWS * WPB);   // 1024 blocks

// Scheduler fence: memory ops cannot cross. Bounds twiddle-load hoisting
// so register pressure stays under the RA grant. Costs no instructions.
#define SCHED_FENCE() asm volatile("" ::: "memory")

// Cross-lane partner (lane ^ M), cheapest pipe per mask.
template <int M>
__device__ __forceinline__ float part_xor(float x) {
    if constexpr (M == 1)        // quad_perm [1,0,3,2]
        return __int_as_float(__builtin_amdgcn_mov_dpp(__float_as_int(x), 0xB1, 0xF, 0xF, true));
    else if constexpr (M == 2)   // quad_perm [2,3,0,1]
        return __int_as_float(__builtin_amdgcn_mov_dpp(__float_as_int(x), 0x4E, 0xF, 0xF, true));
    else if constexpr (M == 4)   // xor 4 within 32-half
        return __int_as_float(__builtin_amdgcn_ds_swizzle(__float_as_int(x), 0x101F));
    else if constexpr (M == 8)
        return __int_as_float(__builtin_amdgcn_ds_swizzle(__float_as_int(x), 0x201F));
    else if constexpr (M == 16)
        return __int_as_float(__builtin_amdgcn_ds_swizzle(__float_as_int(x), 0x401F));
    else
        return __shfl_xor(x, 32, 64);
}

// stages 1..6 (s=2..64): pair bit is a lane bit -> cross-lane partner.
// Twiddles L2-direct. cm = coeff of my value, cp = coeff of partner value:
//   hiHalf=0: out = t2.x*mine + t2.y*part ; hiHalf=1: out = t2.y*mine + t2.x*part
template <int ST>
__device__ __forceinline__ void mid_stage(float (&v)[ROWS][32], const float* twst, int lane) {
    constexpr int s = 1 << ST;
    constexpr int m = 1 << (ST - 1);
    const int hiHalf = (lane >> (ST - 1)) & 1;
    const int l2 = lane * 2;
    #pragma unroll
    for (int k = 0; k < 32; ++k) {
        const int e = (k >> 1) * 128 + l2 + (k & 1);
        const int p = ((e >> (ST + 1)) << ST) | (e & (s - 1));
        const float2 t2 = *(const float2*)(twst + 4 * p + 2 * hiHalf);
        const float cm = hiHalf ? t2.y : t2.x;   // 2 cndmask per k, shared over rows
        const float cp = hiHalf ? t2.x : t2.y;
        #pragma unroll
        for (int rr = 0; rr < ROWS; ++rr) {
            const float mine = v[rr][k];
            const float part = part_xor<m>(mine);
            v[rr][k] = fmaf(cm, mine, cp * part);
        }
        if ((k & 7) == 7) SCHED_FENCE();   // bound in-flight float2 loads at ~8
    }
}

// stages 7..10 (s=128..1024): pair bit is an r bit -> in-register
template <int ST>
__device__ __forceinline__ void hi_stage(float (&v)[ROWS][32], const float* twst, int lane) {
    constexpr int s = 1 << ST;
    constexpr int rm = 1 << (ST - 7);
    const int l2 = lane * 2;
    #pragma unroll
    for (int r = 0; r < 16; ++r) {
        if (r & rm) continue;                  // visit each pair at lo (compile-time)
        #pragma unroll
        for (int j = 0; j < 2; ++j) {
            const int e = r * 128 + l2 + j;
            const int p = ((e >> (ST + 1)) << ST) | (e & (s - 1));
            const float4 t4 = *(const float4*)(twst + 4 * p);
            const int klo = 2 * r + j;
            const int khi = 2 * (r + rm) + j;
            #pragma unroll
            for (int rr = 0; rr < ROWS; ++rr) {
                const float lo = v[rr][klo];
                const float hi = v[rr][khi];
                v[rr][klo] = fmaf(t4.x, lo, t4.y * hi);
                v[rr][khi] = fmaf(t4.z, lo, t4.w * hi);
            }
        }
        if ((r & 1) == 1) SCHED_FENCE();   // bound in-flight float4 loads at ~4
    }
}

__global__ __launch_bounds__(BLOCK, 1)
void butterfly_kernel(const float* __restrict__ x,
                      const float* __restrict__ tw,
                      const float* __restrict__ bias,
                      float* __restrict__ out)
{
    const int tid = threadIdx.x;
    const int lane = tid & 63;
    const int w = tid >> 6;
    const int wid = blockIdx.x * WPB + w;
    const size_t row0 = (size_t)wid * ROWS;
    const int l2 = lane * 2;

    float v[ROWS][32];

    // ---- coalesced float2 x loads (512 B per wave-inst); write v directly.
    #pragma unroll
    for (int rr = 0; rr < ROWS; ++rr) {
        const float* src = x + (row0 + rr) * N + l2;
        #pragma unroll
        for (int r = 0; r < 16; ++r) {
            const float2 f = *(const float2*)(src + r * 128);
            v[rr][2*r]   = f.x;
            v[rr][2*r+1] = f.y;
        }
    }

    // ---- stage 0 (s=1): in-lane pair (j bit), coalesced float4 twiddle
    #pragma unroll
    for (int r = 0; r < 16; ++r) {
        const float4 t4 = *(const float4*)(tw + 4 * (r * 64 + lane));
        #pragma unroll
        for (int rr = 0; rr < ROWS; ++rr) {
            const float lo = v[rr][2*r];
            const float hi = v[rr][2*r+1];
            v[rr][2*r]   = fmaf(t4.x, lo, t4.y * hi);
            v[rr][2*r+1] = fmaf(t4.z, lo, t4.w * hi);
        }
        if ((r & 3) == 3) SCHED_FENCE();
    }

    // ---- stages 1..6: cross-lane, twiddles L2-direct
    mid_stage<1>(v, tw + (1 << 12), lane);
    mid_stage<2>(v, tw + (2 << 12), lane);
    mid_stage<3>(v, tw + (3 << 12), lane);
    mid_stage<4>(v, tw + (4 << 12), lane);
    mid_stage<5>(v, tw + (5 << 12), lane);
    mid_stage<6>(v, tw + (6 << 12), lane);

    // ---- stages 7..10: in-register, twiddles L2-direct
    hi_stage<7>(v, tw + (7 << 12), lane);
    hi_stage<8>(v, tw + (8 << 12), lane);
    hi_stage<9>(v, tw + (9 << 12), lane);
    hi_stage<10>(v, tw + (10 << 12), lane);

    // ---- coalesced float2 stores with bias (bias shared across rows)
    #pragma unroll
    for (int r = 0; r < 16; ++r) {
        const float2 b = *(const float2*)(bias + r * 128 + l2);
        #pragma unroll
        for (int rr = 0; rr < ROWS; ++rr) {
            float2 o;
            o.x = v[rr][2*r]   + b.x;
            o.y = v[rr][2*r+1] + b.y;
            *(float2*)(out + (row0 + rr) * N + r * 128 + l2) = o;
        }
    }
}

extern "C" void kernel_launch(void* const* d_in, const int* in_sizes, int n_in,
                              void* d_out, int out_size, void* d_ws, size_t ws_size,
                              hipStream_t stream) {
    const float* x    = (const float*)d_in[0];
    const float* tw   = (const float*)d_in[1];
    const float* bias = (const float*)d_in[2];
    float* out = (float*)d_out;

    butterfly_kernel<<<GRID, BLOCK, 0, stream>>>(x, tw, bias, out);
}